// Round 4
// baseline (211.355 us; speedup 1.0000x reference)
//
#include <hip/hip_runtime.h>

// RelScaleAttend: b=4, 16 heads, s=1024 (32x32 img), d=64. Single fused kernel.
// Block = (h-pair, bh): 64 queries, 4 waves x 16 queries. K-tile = 32 keys
// (= one image row, so kh == kt and rel_w is tile-invariant).
// Phase 0: exact fp32 rel tables (x log2e) + per-query max-bound M (static max:
//   every (kh,kw) pair occurs, so M = max_kh + max_kw bounds the true row max
//   within +-|qk|/8*log2e -> no running max / rescale needed, exact math).
// Phase 1: bf16-MFMA flash loop with DOUBLE-BUFFERED K/V LDS and a RAW
//   barrier (s_waitcnt lgkmcnt(0) only + s_barrier): global prefetch loads
//   stay in flight across the barrier (cp.async-style), unlike __syncthreads
//   which drains vmcnt(0) and serializes the pipeline.

#define SCALE2 0.18033688f   // 0.125 * log2(e)
#define LOG2E  1.44269504f

typedef float  f32x4  __attribute__((ext_vector_type(4)));
typedef __bf16 bf16x8 __attribute__((ext_vector_type(8)));
typedef __bf16 bf16x4 __attribute__((ext_vector_type(4)));
typedef __bf16 bf16x2 __attribute__((ext_vector_type(2)));

// Barrier that waits only on LDS ops (lgkmcnt(0)); leaves global loads
// (vmcnt) in flight. 0xC07F = vmcnt(63) expcnt(7) lgkmcnt(0).
__device__ __forceinline__ void ldsbar() {
    __asm__ volatile("" ::: "memory");
    __builtin_amdgcn_s_waitcnt(0xC07F);
    __builtin_amdgcn_s_barrier();
    __asm__ volatile("" ::: "memory");
}

__global__ __launch_bounds__(256, 3) void attn(
        const float* __restrict__ qg, const float* __restrict__ kg,
        const float* __restrict__ vg,
        const float* __restrict__ rph, const float* __restrict__ rpw,
        float* __restrict__ outg) {
    // LDS (41984 B -> 3 blocks/CU):
    //   RelH/RelW 64x34 f32 (8704 B each), MH 1 KB,
    //   arena 23552 B: phase0 = Ql 64x68 f32 (17408 B);
    //   phase1 = Kb 2x(32x72) + Vb 2x(64x36) + Pl 4x(16x40), all bf16.
    __shared__ float RelH[64 * 34];
    __shared__ float RelW[64 * 34];
    __shared__ float MH[4 * 64];
    __shared__ __align__(16) __bf16 arena[11776];
    float*  Ql = (float*)arena;
    __bf16* Kb = arena;                 // 2 x 2304
    __bf16* Vb = arena + 4608;          // 2 x 2304
    __bf16* Pl = arena + 9216;          // 2560

    const int tid  = threadIdx.x;
    const int w    = tid >> 6, lane = tid & 63;
    const int quad = lane >> 4, n16 = lane & 15;
    const int hp = blockIdx.x, bh = blockIdx.y;
    const int bb = bh >> 4, nh = bh & 15;
    const int h0 = hp << 1;
    const int base = bb * 1048576 + nh * 64;   // per-head element base
    const int sq0  = h0 * 32;                  // first query row of block

    const int krow = tid >> 3, kc0 = (tid & 7) << 3;   // K staging coords
    const int vc = tid & 63, vk0 = (tid >> 6) << 3;    // V: d=vc, keys vk0..+7
    const int pw = w * 640;                            // per-wave P base

    // ---- issue tile-0 K/V global loads immediately ----
    f32x4 ka, kb2; float vv[8];
    {
        const float* kp = kg + base + krow * 1024 + kc0;
        ka  = ((const f32x4*)kp)[0];
        kb2 = ((const f32x4*)kp)[1];
        const float* vp = vg + base + vk0 * 1024 + vc;
#pragma unroll
        for (int j = 0; j < 8; ++j) vv[j] = vp[j * 1024];
    }

    // ---- stage Q rows (fp32) into LDS, coalesced b128 ----
    {
        int r0 = tid >> 4, c0 = (tid & 15) << 2;
#pragma unroll
        for (int k2 = 0; k2 < 4; ++k2) {
            int row = k2 * 16 + r0;
            *(f32x4*)&Ql[row * 68 + c0] =
                *(const f32x4*)(qg + base + (sq0 + row) * 1024 + c0);
        }
    }
    __syncthreads();

    // ---- phase 0: rel tables (x log2e) + per-slot max ----
    {
        int ql = tid & 63, slot = tid >> 6;
        int isw = slot >> 1, khb = (slot & 1) << 4;
        int hh = h0 + (ql >> 5), wl = ql & 31;
        int row0 = (isw ? wl : hh) + 31 - khb;      // row_j = row0 - j
        const float* tp = (isw ? rpw : rph) + row0 * 64;
        const float* qrow = &Ql[ql * 68];
        float acc[16];
#pragma unroll
        for (int j = 0; j < 16; ++j) acc[j] = 0.f;
#pragma unroll 4
        for (int cq = 0; cq < 16; ++cq) {
            f32x4 qv = *(const f32x4*)(qrow + cq * 4);
#pragma unroll
            for (int j = 0; j < 16; ++j) {
                f32x4 tv = *(const f32x4*)(tp - j * 64 + cq * 4);
                acc[j] += qv.x * tv.x + qv.y * tv.y + qv.z * tv.z + qv.w * tv.w;
            }
        }
        float* dst = (isw ? RelW : RelH) + ql * 34 + khb;
        float hmax = -1e30f;
#pragma unroll
        for (int j = 0; j < 16; ++j) {
            float v = acc[j] * LOG2E;
            dst[j] = v;
            hmax = fmaxf(hmax, v);
        }
        MH[slot * 64 + ql] = hmax;
    }

    // ---- Q A-fragments from Ql: A[m=n16][k=quad*8+j], query = w*16+n16 ----
    const int qla = w * 16 + n16;
    bf16x8 qf[2];
#pragma unroll
    for (int ch = 0; ch < 2; ++ch) {
        const float* qp = &Ql[qla * 68 + ch * 32 + quad * 8];
        f32x4 a = ((const f32x4*)qp)[0];
        f32x4 b = ((const f32x4*)qp)[1];
        bf16x8 t;
        t[0] = (__bf16)a.x; t[1] = (__bf16)a.y; t[2] = (__bf16)a.z; t[3] = (__bf16)a.w;
        t[4] = (__bf16)b.x; t[5] = (__bf16)b.y; t[6] = (__bf16)b.z; t[7] = (__bf16)b.w;
        qf[ch] = t;
    }
    __syncthreads();   // Rel/MH ready; Ql dead -> arena becomes Kb/Vb/Pl

    // C/D rows this lane owns: local query = w*16 + quad*4 + r
    int qlr[4];
#pragma unroll
    for (int r = 0; r < 4; ++r) qlr[r] = w * 16 + quad * 4 + r;

    // per-row static max M and (rel_w - M); rel_w is tile-invariant
    float rwm[4][2];
#pragma unroll
    for (int r = 0; r < 4; ++r) {
        int q = qlr[r];
        float M = fmaxf(MH[q], MH[64 + q]) + fmaxf(MH[128 + q], MH[192 + q]);
        rwm[r][0] = RelW[q * 34 + n16] - M;
        rwm[r][1] = RelW[q * 34 + 16 + n16] - M;
    }

    float lr[4] = {0.f, 0.f, 0.f, 0.f};
    f32x4 oc[4];
#pragma unroll
    for (int i = 0; i < 4; ++i) oc[i] = (f32x4){0.f, 0.f, 0.f, 0.f};

    // ---- store tile 0 into buffer 0 ----
    {
        bf16x8 t;
        t[0] = (__bf16)ka.x;  t[1] = (__bf16)ka.y;  t[2] = (__bf16)ka.z;  t[3] = (__bf16)ka.w;
        t[4] = (__bf16)kb2.x; t[5] = (__bf16)kb2.y; t[6] = (__bf16)kb2.z; t[7] = (__bf16)kb2.w;
        *(bf16x8*)&Kb[krow * 72 + kc0] = t;
#pragma unroll
        for (int j = 0; j < 4; ++j) {
            bf16x2 p; p[0] = (__bf16)vv[2 * j]; p[1] = (__bf16)vv[2 * j + 1];
            *(bf16x2*)&Vb[vc * 36 + vk0 + 2 * j] = p;
        }
    }

    for (int kt = 0; kt < 32; ++kt) {
        const int cur = kt & 1;
        // ---- issue global prefetch of tile kt+1 (crosses the raw barrier) ----
        if (kt < 31) {
            const float* kp = kg + base + ((kt + 1) * 32 + krow) * 1024 + kc0;
            ka  = ((const f32x4*)kp)[0];
            kb2 = ((const f32x4*)kp)[1];
            const float* vp = vg + base + ((kt + 1) * 32 + vk0) * 1024 + vc;
#pragma unroll
            for (int j = 0; j < 8; ++j) vv[j] = vp[j * 1024];
        }
        ldsbar();                      // buf[cur] visible; vmem stays in flight
        const __bf16* Kl = Kb + cur * 2304;
        const __bf16* Vl = Vb + cur * 2304;

        float rh[4];
#pragma unroll
        for (int r = 0; r < 4; ++r) rh[r] = RelH[qlr[r] * 34 + kt];

        // ---- S = Q K^T : 4 MFMAs (2 key groups x 2 c-halves) ----
        f32x4 s0 = {0.f, 0.f, 0.f, 0.f}, s1 = s0;
#pragma unroll
        for (int ch = 0; ch < 2; ++ch) {
            bf16x8 k0 = *(const bf16x8*)&Kl[n16 * 72 + ch * 32 + quad * 8];
            bf16x8 k1 = *(const bf16x8*)&Kl[(16 + n16) * 72 + ch * 32 + quad * 8];
            s0 = __builtin_amdgcn_mfma_f32_16x16x32_bf16(qf[ch], k0, s0, 0, 0, 0);
            s1 = __builtin_amdgcn_mfma_f32_16x16x32_bf16(qf[ch], k1, s1, 0, 0, 0);
        }

        // ---- static-max softmax: p = exp2(s*SCALE2 + rh + rw - M) ----
#pragma unroll
        for (int r = 0; r < 4; ++r) {
            float p0 = exp2f(fmaf(s0[r], SCALE2, rh[r] + rwm[r][0]));
            float p1 = exp2f(fmaf(s1[r], SCALE2, rh[r] + rwm[r][1]));
            lr[r] += p0 + p1;
            int pr = pw + (quad * 4 + r) * 40;
            Pl[pr + n16]      = (__bf16)p0;
            Pl[pr + 16 + n16] = (__bf16)p1;
        }

        // ---- O += P V (P C-layout -> A-layout via per-wave LDS) ----
        bf16x8 pf = *(const bf16x8*)&Pl[pw + n16 * 40 + quad * 8];
#pragma unroll
        for (int cn = 0; cn < 4; ++cn) {
            const __bf16* vp2 = &Vl[(cn * 16 + n16) * 36 + quad * 8];
            bf16x4 a = *(const bf16x4*)vp2;
            bf16x4 b = *(const bf16x4*)(vp2 + 4);
            bf16x8 vf;
            vf[0] = a[0]; vf[1] = a[1]; vf[2] = a[2]; vf[3] = a[3];
            vf[4] = b[0]; vf[5] = b[1]; vf[6] = b[2]; vf[7] = b[3];
            oc[cn] = __builtin_amdgcn_mfma_f32_16x16x32_bf16(pf, vf, oc[cn], 0, 0, 0);
        }

        // ---- convert + store prefetched tile kt+1 -> buf[cur^1] ----
        if (kt < 31) {
            __bf16* Kn = Kb + (cur ^ 1) * 2304;
            __bf16* Vn = Vb + (cur ^ 1) * 2304;
            bf16x8 t;
            t[0] = (__bf16)ka.x;  t[1] = (__bf16)ka.y;  t[2] = (__bf16)ka.z;  t[3] = (__bf16)ka.w;
            t[4] = (__bf16)kb2.x; t[5] = (__bf16)kb2.y; t[6] = (__bf16)kb2.z; t[7] = (__bf16)kb2.w;
            *(bf16x8*)&Kn[krow * 72 + kc0] = t;
#pragma unroll
            for (int j = 0; j < 4; ++j) {
                bf16x2 p; p[0] = (__bf16)vv[2 * j]; p[1] = (__bf16)vv[2 * j + 1];
                *(bf16x2*)&Vn[vc * 36 + vk0 + 2 * j] = p;
            }
        }
    }

    // ---- epilogue: one l-reduction across the 16-lane row group, store ----
#pragma unroll
    for (int r = 0; r < 4; ++r) {
        float l = lr[r];
        l += __shfl_xor(l, 1);
        l += __shfl_xor(l, 2);
        l += __shfl_xor(l, 4);
        l += __shfl_xor(l, 8);
        float inv = 1.f / l;
        int ob = base + (sq0 + qlr[r]) * 1024 + n16;
        outg[ob]      = oc[0][r] * inv;
        outg[ob + 16] = oc[1][r] * inv;
        outg[ob + 32] = oc[2][r] * inv;
        outg[ob + 48] = oc[3][r] * inv;
    }
}

extern "C" void kernel_launch(void* const* d_in, const int* in_sizes, int n_in,
                              void* d_out, int out_size, void* d_ws, size_t ws_size,
                              hipStream_t stream) {
    (void)in_sizes; (void)n_in; (void)out_size; (void)d_ws; (void)ws_size;
    const float* q   = (const float*)d_in[0];
    const float* k   = (const float*)d_in[1];
    const float* v   = (const float*)d_in[2];
    const float* rph = (const float*)d_in[3];
    const float* rpw = (const float*)d_in[4];
    dim3 g(16, 64);                      // (h-pair, bh)
    attn<<<g, 256, 0, stream>>>(q, k, v, rph, rpw, (float*)d_out);
}